// Round 5
// baseline (381.034 us; speedup 1.0000x reference)
//
#include <hip/hip_runtime.h>

// ---------------------------------------------------------------------------
// Attention: out = softmax(BETA * (X_q Wq + bq)(X_k Wk + bk)^T) (X_v Wv + bv)
// B=4, S=2048, D=1024, KEY_DIM=VALUE_DIM=1024, BETA=1/32.
// R5: correctness restore + structural occupancy.
//  - REVERTED __launch_bounds__(256,3): bound < real reg need (188) forced
//    spills -> flaky under graph replay (R4 post-timing divergence). Plain 256.
//  - scores GEMM: TN=128 -> TN=64 (acc 32 AGPR, ~132 regs total) -> 3
//    waves/SIMD naturally, same regime as PV kernel. Grid (32,16,4).
//  - Kept: R3 XOR bank swizzle (conflicts = 0), R4 XCD-aware proj decode.
// ---------------------------------------------------------------------------

typedef __bf16 bf16x8 __attribute__((ext_vector_type(8)));
typedef float f32x4 __attribute__((ext_vector_type(4)));

#define MIB ((size_t)1 << 20)

__device__ __forceinline__ unsigned short f2b(float f) {
  unsigned int u = __float_as_uint(f);
  return (unsigned short)((u + 0x7FFFu + ((u >> 16) & 1u)) >> 16);
}

__device__ __forceinline__ void async16(const void* g, void* l) {
  __builtin_amdgcn_global_load_lds(
      (const __attribute__((address_space(1))) unsigned int*)g,
      (__attribute__((address_space(3))) unsigned int*)l, 16, 0, 0);
}

// ---------------------------------------------------------------------------
// Shared GEMM K-loop: acc += A_tile[128xBK] * Bt_tile[TNxBK]^T, BK=64.
// A: [M,K] bf16 row-major, Bt: [N,K] bf16 row-major.
// 4 waves arranged 2x2; each wave does 64 x (TN/2) via 4 x (TN/32) frags.
// LDS layout: row-major 64 elems/row, 16B chunk column XOR-swizzled by row
// (slot (r,cc) holds global chunk (r, cc^(r&7))) -> conflict-free reads.
// ---------------------------------------------------------------------------
template <int TN>
__device__ __forceinline__ void gemm_loop(
    const unsigned short* __restrict__ A, const unsigned short* __restrict__ Bt,
    unsigned short* lds_a, unsigned short* lds_b, int K, int m0, int n0,
    f32x4 (&acc)[4][TN / 32]) {
  constexpr int NI = TN / 32;
  const int tid = threadIdx.x;
  const int lane = tid & 63;
  const int wave = tid >> 6;
  const int wm = (wave >> 1) * 64;
  const int wn = (wave & 1) * (TN / 2);
  const int fr = lane & 15;
  const int q = lane >> 4;  // quarter-wave -> k-chunk offset

  for (int kb = 0; kb < K; kb += 64) {
#pragma unroll
    for (int i = 0; i < 4; ++i) {
      const int e = i * 256 + tid;  // chunk slot, 8 bf16 per chunk
      const int r = e >> 3;
      const int cg = (e & 7) ^ (r & 7);
      async16(A + (size_t)(m0 + r) * K + kb + cg * 8, &lds_a[e * 8]);
    }
#pragma unroll
    for (int i = 0; i < TN / 32; ++i) {
      const int e = i * 256 + tid;
      const int r = e >> 3;
      const int cg = (e & 7) ^ (r & 7);
      async16(Bt + (size_t)(n0 + r) * K + kb + cg * 8, &lds_b[e * 8]);
    }
    __syncthreads();

#pragma unroll
    for (int ks = 0; ks < 64; ks += 32) {
      const int kc = (ks >> 3) + q;  // global k-chunk this lane needs
      bf16x8 av[4], bv[NI];
#pragma unroll
      for (int mi = 0; mi < 4; ++mi) {
        const int R = wm + mi * 16 + fr;
        av[mi] = *(const bf16x8*)&lds_a[R * 64 + ((kc ^ (R & 7)) << 3)];
      }
#pragma unroll
      for (int ni = 0; ni < NI; ++ni) {
        const int R = wn + ni * 16 + fr;
        bv[ni] = *(const bf16x8*)&lds_b[R * 64 + ((kc ^ (R & 7)) << 3)];
      }
#pragma unroll
      for (int mi = 0; mi < 4; ++mi)
#pragma unroll
        for (int ni = 0; ni < NI; ++ni)
          acc[mi][ni] = __builtin_amdgcn_mfma_f32_16x16x32_bf16(
              av[mi], bv[ni], acc[mi][ni], 0, 0, 0);
    }
    __syncthreads();
  }
}

// ---------------------------------------------------------------------------
// Merged projection GEMM, XCD-swizzled 1D grid of 1536 blocks.
// Decode: xcd = id&7 (HW round-robin), then n fastest, 8 m-tiles per
// (xcd, z) stripe -> A-stripe fetched once per XCD, WT (2 MiB) L2-resident.
// z=0,1: bf16 row-major out [8192,1024]; z=2: vT[b][n][s] transposed out.
// ---------------------------------------------------------------------------
struct ProjArgs {
  const unsigned short* A[3];
  const unsigned short* Bt[3];
  unsigned short* C[3];
  const float* bias[3];
};

__global__ __launch_bounds__(256) void proj_gemm(ProjArgs p) {
  __shared__ __align__(16) unsigned short lds_a[128 * 64];
  __shared__ __align__(16) unsigned short lds_b[128 * 64];

  const int id = blockIdx.x;
  const int xcd = id & 7;
  const int s = id >> 3;       // 0..191 within XCD
  const int n_t = s & 7;       // n fastest: shares A-stripe within XCD
  const int t = s >> 3;        // 0..23
  const int m_l = t & 7;       // 8 m-tiles per (xcd, z)
  const int z = t >> 3;        // 0..2
  const int m0 = (xcd * 8 + m_l) * 128;
  const int n0 = n_t * 128;

  f32x4 acc[4][4] = {};
  gemm_loop<128>(p.A[z], p.Bt[z], lds_a, lds_b, 1024, m0, n0, acc);

  const int lane = threadIdx.x & 63;
  const int wave = threadIdx.x >> 6;
  const int wm = (wave >> 1) * 64;
  const int wn = (wave & 1) * 64;
  const int fr = lane & 15;
  const float* bias = p.bias[z];

  // C/D layout (m89/m91): col = lane&15 (+frag n), row = (lane>>4)*4 + reg.
  if (z != 2) {
    unsigned short* C = p.C[z];
#pragma unroll
    for (int mi = 0; mi < 4; ++mi) {
#pragma unroll
      for (int ni = 0; ni < 4; ++ni) {
        const int col = n0 + wn + ni * 16 + fr;
        const float bb = bias[col];
        const int rowb = m0 + wm + mi * 16 + (lane >> 4) * 4;
#pragma unroll
        for (int r = 0; r < 4; ++r)
          C[(size_t)(rowb + r) * 1024 + col] = f2b(acc[mi][ni][r] + bb);
      }
    }
  } else {
    // vT: per-batch [1024, 2048]; batch uniform per tile (m0 % 128 == 0).
    unsigned short* C = p.C[2] + (size_t)(m0 >> 11) * (2048 * 1024);
#pragma unroll
    for (int mi = 0; mi < 4; ++mi) {
#pragma unroll
      for (int ni = 0; ni < 4; ++ni) {
        const int col = n0 + wn + ni * 16 + fr;
        const float bb = bias[col];
        const int rowb = (m0 + wm + mi * 16 + (lane >> 4) * 4) & 2047;
        ushort4 o = make_ushort4(f2b(acc[mi][ni][0] + bb), f2b(acc[mi][ni][1] + bb),
                                 f2b(acc[mi][ni][2] + bb), f2b(acc[mi][ni][3] + bb));
        *(ushort4*)&C[(size_t)col * 2048 + rowb] = o;
      }
    }
  }
}

// ---------------------------------------------------------------------------
// Batched GEMM, fp32 out: C[bz][m,n] = sum_k A[bz][m,k] * Bt[bz][n,k]
// TN=64 for both scores and PV: acc[4][2]=32 AGPR -> ~132 regs total ->
// 3 waves/SIMD without launch_bounds coercion.
// ---------------------------------------------------------------------------
template <int TN>
__global__ __launch_bounds__(256) void gemm_f32(
    const unsigned short* __restrict__ A, const unsigned short* __restrict__ Bt,
    float* __restrict__ C, int K, int ldc, long long sA, long long sB,
    long long sC) {
  __shared__ __align__(16) unsigned short lds_a[128 * 64];
  __shared__ __align__(16) unsigned short lds_b[TN * 64];
  const int bz = blockIdx.z;
  A += (long long)bz * sA;
  Bt += (long long)bz * sB;
  C += (long long)bz * sC;
  const int m0 = blockIdx.y * 128;
  const int n0 = blockIdx.x * TN;

  f32x4 acc[4][TN / 32] = {};
  gemm_loop<TN>(A, Bt, lds_a, lds_b, K, m0, n0, acc);

  const int lane = threadIdx.x & 63;
  const int wave = threadIdx.x >> 6;
  const int wm = (wave >> 1) * 64;
  const int wn = (wave & 1) * (TN / 2);
  const int fr = lane & 15;
#pragma unroll
  for (int mi = 0; mi < 4; ++mi) {
#pragma unroll
    for (int ni = 0; ni < TN / 32; ++ni) {
      const int col = n0 + wn + ni * 16 + fr;
      const int rowb = m0 + wm + mi * 16 + (lane >> 4) * 4;
#pragma unroll
      for (int r = 0; r < 4; ++r)
        C[(size_t)(rowb + r) * ldc + col] = acc[mi][ni][r];
    }
  }
}

// ---------------------------------------------------------------------------
// Merged cast fp32 -> bf16: blockIdx.y selects tensor {q,k,v}.
// ---------------------------------------------------------------------------
__global__ __launch_bounds__(256) void cast3(
    const float4* __restrict__ a, const float4* __restrict__ b,
    const float4* __restrict__ c, ushort4* __restrict__ oa,
    ushort4* __restrict__ ob, ushort4* __restrict__ oc, int n4) {
  const int i = blockIdx.x * 256 + threadIdx.x;
  if (i >= n4) return;
  const float4* src = (blockIdx.y == 0) ? a : (blockIdx.y == 1) ? b : c;
  ushort4* dst = (blockIdx.y == 0) ? oa : (blockIdx.y == 1) ? ob : oc;
  float4 v = src[i];
  dst[i] = make_ushort4(f2b(v.x), f2b(v.y), f2b(v.z), f2b(v.w));
}

// ---------------------------------------------------------------------------
// Merged cast + transpose W [K,N] fp32 -> WT [N,K] bf16; z selects weight.
// ---------------------------------------------------------------------------
__global__ __launch_bounds__(256) void transpose3(
    const float* __restrict__ w0, const float* __restrict__ w1,
    const float* __restrict__ w2, unsigned short* __restrict__ t0,
    unsigned short* __restrict__ t1, unsigned short* __restrict__ t2) {
  __shared__ float t[32][33];
  const int K = 1024, N = 1024;
  const float* W = (blockIdx.z == 0) ? w0 : (blockIdx.z == 1) ? w1 : w2;
  unsigned short* WT = (blockIdx.z == 0) ? t0 : (blockIdx.z == 1) ? t1 : t2;
  const int n0 = blockIdx.x * 32, k0 = blockIdx.y * 32;
  const int tx = threadIdx.x, ty = threadIdx.y;  // block (32,8)
#pragma unroll
  for (int i = 0; i < 32; i += 8)
    t[ty + i][tx] = W[(size_t)(k0 + ty + i) * N + (n0 + tx)];
  __syncthreads();
#pragma unroll
  for (int i = 0; i < 32; i += 8)
    WT[(size_t)(n0 + ty + i) * K + (k0 + tx)] = f2b(t[tx][ty + i]);
}

// ---------------------------------------------------------------------------
// Row softmax: P[row,:] = softmax(BETA * S[row,:]) as bf16. One block/row.
// ---------------------------------------------------------------------------
__global__ __launch_bounds__(256) void softmax_rows(const float* __restrict__ S,
                                                    unsigned short* __restrict__ P) {
  const int cols = 2048;
  const size_t row = blockIdx.x;
  const float4* srow = (const float4*)(S + row * cols);
  const int tid = threadIdx.x;
  const int lane = tid & 63;
  const int wave = tid >> 6;

  float4 a = srow[tid];
  float4 b = srow[tid + 256];

  float mx = fmaxf(fmaxf(fmaxf(a.x, a.y), fmaxf(a.z, a.w)),
                   fmaxf(fmaxf(b.x, b.y), fmaxf(b.z, b.w)));
#pragma unroll
  for (int o = 1; o < 64; o <<= 1) mx = fmaxf(mx, __shfl_xor(mx, o));

  __shared__ float red[8];
  if (lane == 0) red[wave] = mx;
  __syncthreads();
  mx = fmaxf(fmaxf(red[0], red[1]), fmaxf(red[2], red[3]));

  const float c = 0.03125f * 1.4426950408889634f;  // BETA * log2(e)
  float4 pa, pb;
  pa.x = exp2f((a.x - mx) * c); pa.y = exp2f((a.y - mx) * c);
  pa.z = exp2f((a.z - mx) * c); pa.w = exp2f((a.w - mx) * c);
  pb.x = exp2f((b.x - mx) * c); pb.y = exp2f((b.y - mx) * c);
  pb.z = exp2f((b.z - mx) * c); pb.w = exp2f((b.w - mx) * c);

  float sum = pa.x + pa.y + pa.z + pa.w + pb.x + pb.y + pb.z + pb.w;
#pragma unroll
  for (int o = 1; o < 64; o <<= 1) sum += __shfl_xor(sum, o);
  if (lane == 0) red[4 + wave] = sum;
  __syncthreads();
  sum = red[4] + red[5] + red[6] + red[7];

  const float inv = 1.0f / sum;
  ushort4* prow = (ushort4*)(P + row * cols);
  prow[tid] = make_ushort4(f2b(pa.x * inv), f2b(pa.y * inv), f2b(pa.z * inv),
                           f2b(pa.w * inv));
  prow[tid + 256] = make_ushort4(f2b(pb.x * inv), f2b(pb.y * inv),
                                 f2b(pb.z * inv), f2b(pb.w * inv));
}

// ---------------------------------------------------------------------------
extern "C" void kernel_launch(void* const* d_in, const int* in_sizes, int n_in,
                              void* d_out, int out_size, void* d_ws, size_t ws_size,
                              hipStream_t stream) {
  const float* query = (const float*)d_in[0];
  const float* key_ = (const float*)d_in[1];
  const float* value = (const float*)d_in[2];
  const float* Wq = (const float*)d_in[3];
  const float* bq = (const float*)d_in[4];
  const float* Wk = (const float*)d_in[5];
  const float* bk = (const float*)d_in[6];
  const float* Wv = (const float*)d_in[7];
  const float* bv = (const float*)d_in[8];
  float* out = (float*)d_out;

  char* ws = (char*)d_ws;
  // Workspace layout (peak 166 MiB):
  //   [0,6)      WqT/WkT/WvT bf16 [1024,1024]
  //   [6,54)     Xq/Xk/Xv bf16 [8192,1024]   (reused for P after projections)
  //   [54,102)   q bf16 [8192,1024], k bf16 [8192,1024], vT bf16 [4][1024,2048]
  //   [102,166)  scores fp32 [4,2048,2048]
  unsigned short* WqT = (unsigned short*)ws;
  unsigned short* WkT = WqT + (size_t)1024 * 1024;
  unsigned short* WvT = WkT + (size_t)1024 * 1024;
  unsigned short* Xq = (unsigned short*)(ws + 6 * MIB);
  unsigned short* Xk = Xq + (size_t)8192 * 1024;
  unsigned short* Xv = Xk + (size_t)8192 * 1024;
  unsigned short* qb = (unsigned short*)(ws + 54 * MIB);
  unsigned short* kb = (unsigned short*)(ws + 70 * MIB);
  unsigned short* vT = (unsigned short*)(ws + 86 * MIB);
  float* sc = (float*)(ws + 102 * MIB);
  unsigned short* P = (unsigned short*)(ws + 6 * MIB);  // reuse X region

  const int n4 = (4 * 2048 * 1024) / 4;
  cast3<<<dim3(n4 / 256, 3), 256, 0, stream>>>(
      (const float4*)query, (const float4*)key_, (const float4*)value,
      (ushort4*)Xq, (ushort4*)Xk, (ushort4*)Xv, n4);

  transpose3<<<dim3(32, 32, 3), dim3(32, 8), 0, stream>>>(Wq, Wk, Wv, WqT, WkT,
                                                          WvT);

  // All three projections, XCD-swizzled 1D grid of 1536 blocks.
  ProjArgs pa;
  pa.A[0] = Xq;  pa.A[1] = Xk;  pa.A[2] = Xv;
  pa.Bt[0] = WqT; pa.Bt[1] = WkT; pa.Bt[2] = WvT;
  pa.C[0] = qb;  pa.C[1] = kb;  pa.C[2] = vT;
  pa.bias[0] = bq; pa.bias[1] = bk; pa.bias[2] = bv;
  proj_gemm<<<1536, 256, 0, stream>>>(pa);

  // scores[b] = q[b] @ k[b]^T : M=N=2048, K=1024, fp32 out. TN=64 -> 2048 blocks.
  gemm_f32<64><<<dim3(32, 16, 4), 256, 0, stream>>>(
      qb, kb, sc, 1024, 2048, 2048LL * 1024, 2048LL * 1024, 2048LL * 2048);

  // P = softmax(BETA * scores), bf16
  softmax_rows<<<8192, 256, 0, stream>>>(sc, P);

  // out[b] = P[b] @ v[b] : M=2048, N=1024, K=2048. TN=64 -> 1024 blocks.
  gemm_f32<64><<<dim3(16, 16, 4), 256, 0, stream>>>(
      P, vT, out, 2048, 1024, 2048LL * 2048, 1024LL * 2048, 2048LL * 1024);
}

// Round 6
// 343.131 us; speedup vs baseline: 1.1105x; 1.1105x over previous
//
#include <hip/hip_runtime.h>

// ---------------------------------------------------------------------------
// Attention: out = softmax(BETA * (X_q Wq + bq)(X_k Wk + bk)^T) (X_v Wv + bv)
// B=4, S=2048, D=1024, KEY_DIM=VALUE_DIM=1024, BETA=1/32.
// R6:
//  - proj grid decode REVERTED to R3 z-grid (x-fastest). R5's XCD swizzle cut
//    FETCH 200->54 MB but ran 45% slower: kernel is latency-bound, not
//    fetch-bound; R3's "one n-tile per XCD, stream A" shape was better.
//  - proj TN=128 -> TN=64: acc 32 AGPR, ~164 regs -> 3 waves/SIMD naturally
//    (same regime as gemm_f32<64>, the best kernel so far). Grid (16,64,3).
//  - scores/PV keep R5 TN=64. No __launch_bounds__ coercion anywhere (R4).
// ---------------------------------------------------------------------------

typedef __bf16 bf16x8 __attribute__((ext_vector_type(8)));
typedef float f32x4 __attribute__((ext_vector_type(4)));

#define MIB ((size_t)1 << 20)

__device__ __forceinline__ unsigned short f2b(float f) {
  unsigned int u = __float_as_uint(f);
  return (unsigned short)((u + 0x7FFFu + ((u >> 16) & 1u)) >> 16);
}

__device__ __forceinline__ void async16(const void* g, void* l) {
  __builtin_amdgcn_global_load_lds(
      (const __attribute__((address_space(1))) unsigned int*)g,
      (__attribute__((address_space(3))) unsigned int*)l, 16, 0, 0);
}

// ---------------------------------------------------------------------------
// Shared GEMM K-loop: acc += A_tile[128xBK] * Bt_tile[TNxBK]^T, BK=64.
// A: [M,K] bf16 row-major, Bt: [N,K] bf16 row-major.
// 4 waves arranged 2x2; each wave does 64 x (TN/2) via 4 x (TN/32) frags.
// LDS layout: row-major 64 elems/row, 16B chunk column XOR-swizzled by row
// (slot (r,cc) holds global chunk (r, cc^(r&7))) -> conflict-free reads.
// ---------------------------------------------------------------------------
template <int TN>
__device__ __forceinline__ void gemm_loop(
    const unsigned short* __restrict__ A, const unsigned short* __restrict__ Bt,
    unsigned short* lds_a, unsigned short* lds_b, int K, int m0, int n0,
    f32x4 (&acc)[4][TN / 32]) {
  constexpr int NI = TN / 32;
  const int tid = threadIdx.x;
  const int lane = tid & 63;
  const int wave = tid >> 6;
  const int wm = (wave >> 1) * 64;
  const int wn = (wave & 1) * (TN / 2);
  const int fr = lane & 15;
  const int q = lane >> 4;  // quarter-wave -> k-chunk offset

  for (int kb = 0; kb < K; kb += 64) {
#pragma unroll
    for (int i = 0; i < 4; ++i) {
      const int e = i * 256 + tid;  // chunk slot, 8 bf16 per chunk
      const int r = e >> 3;
      const int cg = (e & 7) ^ (r & 7);
      async16(A + (size_t)(m0 + r) * K + kb + cg * 8, &lds_a[e * 8]);
    }
#pragma unroll
    for (int i = 0; i < TN / 32; ++i) {
      const int e = i * 256 + tid;
      const int r = e >> 3;
      const int cg = (e & 7) ^ (r & 7);
      async16(Bt + (size_t)(n0 + r) * K + kb + cg * 8, &lds_b[e * 8]);
    }
    __syncthreads();

#pragma unroll
    for (int ks = 0; ks < 64; ks += 32) {
      const int kc = (ks >> 3) + q;  // global k-chunk this lane needs
      bf16x8 av[4], bv[NI];
#pragma unroll
      for (int mi = 0; mi < 4; ++mi) {
        const int R = wm + mi * 16 + fr;
        av[mi] = *(const bf16x8*)&lds_a[R * 64 + ((kc ^ (R & 7)) << 3)];
      }
#pragma unroll
      for (int ni = 0; ni < NI; ++ni) {
        const int R = wn + ni * 16 + fr;
        bv[ni] = *(const bf16x8*)&lds_b[R * 64 + ((kc ^ (R & 7)) << 3)];
      }
#pragma unroll
      for (int mi = 0; mi < 4; ++mi)
#pragma unroll
        for (int ni = 0; ni < NI; ++ni)
          acc[mi][ni] = __builtin_amdgcn_mfma_f32_16x16x32_bf16(
              av[mi], bv[ni], acc[mi][ni], 0, 0, 0);
    }
    __syncthreads();
  }
}

// ---------------------------------------------------------------------------
// Merged projection GEMM, TN=64, grid (16,64,3): x = n-tile (fastest ->
// per-XCD n-locality as in R3), y = m-tile, z selects {q,k,v}.
// z=0,1: bf16 row-major out [8192,1024]; z=2: vT[b][n][s] transposed out.
// ---------------------------------------------------------------------------
struct ProjArgs {
  const unsigned short* A[3];
  const unsigned short* Bt[3];
  unsigned short* C[3];
  const float* bias[3];
};

__global__ __launch_bounds__(256) void proj_gemm(ProjArgs p) {
  __shared__ __align__(16) unsigned short lds_a[128 * 64];
  __shared__ __align__(16) unsigned short lds_b[64 * 64];

  const int z = blockIdx.z;
  const int m0 = blockIdx.y * 128;
  const int n0 = blockIdx.x * 64;

  f32x4 acc[4][2] = {};
  gemm_loop<64>(p.A[z], p.Bt[z], lds_a, lds_b, 1024, m0, n0, acc);

  const int lane = threadIdx.x & 63;
  const int wave = threadIdx.x >> 6;
  const int wm = (wave >> 1) * 64;
  const int wn = (wave & 1) * 32;
  const int fr = lane & 15;
  const float* bias = p.bias[z];

  // C/D layout (m89/m91): col = lane&15 (+frag n), row = (lane>>4)*4 + reg.
  if (z != 2) {
    unsigned short* C = p.C[z];
#pragma unroll
    for (int mi = 0; mi < 4; ++mi) {
#pragma unroll
      for (int ni = 0; ni < 2; ++ni) {
        const int col = n0 + wn + ni * 16 + fr;
        const float bb = bias[col];
        const int rowb = m0 + wm + mi * 16 + (lane >> 4) * 4;
#pragma unroll
        for (int r = 0; r < 4; ++r)
          C[(size_t)(rowb + r) * 1024 + col] = f2b(acc[mi][ni][r] + bb);
      }
    }
  } else {
    // vT: per-batch [1024, 2048]; batch uniform per tile (m0 % 128 == 0).
    unsigned short* C = p.C[2] + (size_t)(m0 >> 11) * (2048 * 1024);
#pragma unroll
    for (int mi = 0; mi < 4; ++mi) {
#pragma unroll
      for (int ni = 0; ni < 2; ++ni) {
        const int col = n0 + wn + ni * 16 + fr;
        const float bb = bias[col];
        const int rowb = (m0 + wm + mi * 16 + (lane >> 4) * 4) & 2047;
        ushort4 o = make_ushort4(f2b(acc[mi][ni][0] + bb), f2b(acc[mi][ni][1] + bb),
                                 f2b(acc[mi][ni][2] + bb), f2b(acc[mi][ni][3] + bb));
        *(ushort4*)&C[(size_t)col * 2048 + rowb] = o;
      }
    }
  }
}

// ---------------------------------------------------------------------------
// Batched GEMM, fp32 out: C[bz][m,n] = sum_k A[bz][m,k] * Bt[bz][n,k]
// TN=64: acc[4][2]=32 AGPR -> 3 waves/SIMD without launch_bounds coercion.
// ---------------------------------------------------------------------------
template <int TN>
__global__ __launch_bounds__(256) void gemm_f32(
    const unsigned short* __restrict__ A, const unsigned short* __restrict__ Bt,
    float* __restrict__ C, int K, int ldc, long long sA, long long sB,
    long long sC) {
  __shared__ __align__(16) unsigned short lds_a[128 * 64];
  __shared__ __align__(16) unsigned short lds_b[TN * 64];
  const int bz = blockIdx.z;
  A += (long long)bz * sA;
  Bt += (long long)bz * sB;
  C += (long long)bz * sC;
  const int m0 = blockIdx.y * 128;
  const int n0 = blockIdx.x * TN;

  f32x4 acc[4][TN / 32] = {};
  gemm_loop<TN>(A, Bt, lds_a, lds_b, K, m0, n0, acc);

  const int lane = threadIdx.x & 63;
  const int wave = threadIdx.x >> 6;
  const int wm = (wave >> 1) * 64;
  const int wn = (wave & 1) * (TN / 2);
  const int fr = lane & 15;
#pragma unroll
  for (int mi = 0; mi < 4; ++mi) {
#pragma unroll
    for (int ni = 0; ni < TN / 32; ++ni) {
      const int col = n0 + wn + ni * 16 + fr;
      const int rowb = m0 + wm + mi * 16 + (lane >> 4) * 4;
#pragma unroll
      for (int r = 0; r < 4; ++r)
        C[(size_t)(rowb + r) * ldc + col] = acc[mi][ni][r];
    }
  }
}

// ---------------------------------------------------------------------------
// Merged cast fp32 -> bf16: blockIdx.y selects tensor {q,k,v}.
// ---------------------------------------------------------------------------
__global__ __launch_bounds__(256) void cast3(
    const float4* __restrict__ a, const float4* __restrict__ b,
    const float4* __restrict__ c, ushort4* __restrict__ oa,
    ushort4* __restrict__ ob, ushort4* __restrict__ oc, int n4) {
  const int i = blockIdx.x * 256 + threadIdx.x;
  if (i >= n4) return;
  const float4* src = (blockIdx.y == 0) ? a : (blockIdx.y == 1) ? b : c;
  ushort4* dst = (blockIdx.y == 0) ? oa : (blockIdx.y == 1) ? ob : oc;
  float4 v = src[i];
  dst[i] = make_ushort4(f2b(v.x), f2b(v.y), f2b(v.z), f2b(v.w));
}

// ---------------------------------------------------------------------------
// Merged cast + transpose W [K,N] fp32 -> WT [N,K] bf16; z selects weight.
// ---------------------------------------------------------------------------
__global__ __launch_bounds__(256) void transpose3(
    const float* __restrict__ w0, const float* __restrict__ w1,
    const float* __restrict__ w2, unsigned short* __restrict__ t0,
    unsigned short* __restrict__ t1, unsigned short* __restrict__ t2) {
  __shared__ float t[32][33];
  const int K = 1024, N = 1024;
  const float* W = (blockIdx.z == 0) ? w0 : (blockIdx.z == 1) ? w1 : w2;
  unsigned short* WT = (blockIdx.z == 0) ? t0 : (blockIdx.z == 1) ? t1 : t2;
  const int n0 = blockIdx.x * 32, k0 = blockIdx.y * 32;
  const int tx = threadIdx.x, ty = threadIdx.y;  // block (32,8)
#pragma unroll
  for (int i = 0; i < 32; i += 8)
    t[ty + i][tx] = W[(size_t)(k0 + ty + i) * N + (n0 + tx)];
  __syncthreads();
#pragma unroll
  for (int i = 0; i < 32; i += 8)
    WT[(size_t)(n0 + ty + i) * K + (k0 + tx)] = f2b(t[tx][ty + i]);
}

// ---------------------------------------------------------------------------
// Row softmax: P[row,:] = softmax(BETA * S[row,:]) as bf16. One block/row.
// ---------------------------------------------------------------------------
__global__ __launch_bounds__(256) void softmax_rows(const float* __restrict__ S,
                                                    unsigned short* __restrict__ P) {
  const int cols = 2048;
  const size_t row = blockIdx.x;
  const float4* srow = (const float4*)(S + row * cols);
  const int tid = threadIdx.x;
  const int lane = tid & 63;
  const int wave = tid >> 6;

  float4 a = srow[tid];
  float4 b = srow[tid + 256];

  float mx = fmaxf(fmaxf(fmaxf(a.x, a.y), fmaxf(a.z, a.w)),
                   fmaxf(fmaxf(b.x, b.y), fmaxf(b.z, b.w)));
#pragma unroll
  for (int o = 1; o < 64; o <<= 1) mx = fmaxf(mx, __shfl_xor(mx, o));

  __shared__ float red[8];
  if (lane == 0) red[wave] = mx;
  __syncthreads();
  mx = fmaxf(fmaxf(red[0], red[1]), fmaxf(red[2], red[3]));

  const float c = 0.03125f * 1.4426950408889634f;  // BETA * log2(e)
  float4 pa, pb;
  pa.x = exp2f((a.x - mx) * c); pa.y = exp2f((a.y - mx) * c);
  pa.z = exp2f((a.z - mx) * c); pa.w = exp2f((a.w - mx) * c);
  pb.x = exp2f((b.x - mx) * c); pb.y = exp2f((b.y - mx) * c);
  pb.z = exp2f((b.z - mx) * c); pb.w = exp2f((b.w - mx) * c);

  float sum = pa.x + pa.y + pa.z + pa.w + pb.x + pb.y + pb.z + pb.w;
#pragma unroll
  for (int o = 1; o < 64; o <<= 1) sum += __shfl_xor(sum, o);
  if (lane == 0) red[4 + wave] = sum;
  __syncthreads();
  sum = red[4] + red[5] + red[6] + red[7];

  const float inv = 1.0f / sum;
  ushort4* prow = (ushort4*)(P + row * cols);
  prow[tid] = make_ushort4(f2b(pa.x * inv), f2b(pa.y * inv), f2b(pa.z * inv),
                           f2b(pa.w * inv));
  prow[tid + 256] = make_ushort4(f2b(pb.x * inv), f2b(pb.y * inv),
                                 f2b(pb.z * inv), f2b(pb.w * inv));
}

// ---------------------------------------------------------------------------
extern "C" void kernel_launch(void* const* d_in, const int* in_sizes, int n_in,
                              void* d_out, int out_size, void* d_ws, size_t ws_size,
                              hipStream_t stream) {
  const float* query = (const float*)d_in[0];
  const float* key_ = (const float*)d_in[1];
  const float* value = (const float*)d_in[2];
  const float* Wq = (const float*)d_in[3];
  const float* bq = (const float*)d_in[4];
  const float* Wk = (const float*)d_in[5];
  const float* bk = (const float*)d_in[6];
  const float* Wv = (const float*)d_in[7];
  const float* bv = (const float*)d_in[8];
  float* out = (float*)d_out;

  char* ws = (char*)d_ws;
  // Workspace layout (peak 166 MiB):
  //   [0,6)      WqT/WkT/WvT bf16 [1024,1024]
  //   [6,54)     Xq/Xk/Xv bf16 [8192,1024]   (reused for P after projections)
  //   [54,102)   q bf16 [8192,1024], k bf16 [8192,1024], vT bf16 [4][1024,2048]
  //   [102,166)  scores fp32 [4,2048,2048]
  unsigned short* WqT = (unsigned short*)ws;
  unsigned short* WkT = WqT + (size_t)1024 * 1024;
  unsigned short* WvT = WkT + (size_t)1024 * 1024;
  unsigned short* Xq = (unsigned short*)(ws + 6 * MIB);
  unsigned short* Xk = Xq + (size_t)8192 * 1024;
  unsigned short* Xv = Xk + (size_t)8192 * 1024;
  unsigned short* qb = (unsigned short*)(ws + 54 * MIB);
  unsigned short* kb = (unsigned short*)(ws + 70 * MIB);
  unsigned short* vT = (unsigned short*)(ws + 86 * MIB);
  float* sc = (float*)(ws + 102 * MIB);
  unsigned short* P = (unsigned short*)(ws + 6 * MIB);  // reuse X region

  const int n4 = (4 * 2048 * 1024) / 4;
  cast3<<<dim3(n4 / 256, 3), 256, 0, stream>>>(
      (const float4*)query, (const float4*)key_, (const float4*)value,
      (ushort4*)Xq, (ushort4*)Xk, (ushort4*)Xv, n4);

  transpose3<<<dim3(32, 32, 3), dim3(32, 8), 0, stream>>>(Wq, Wk, Wv, WqT, WkT,
                                                          WvT);

  // All three projections: TN=64, grid (16,64,3) = 3072 blocks.
  ProjArgs pa;
  pa.A[0] = Xq;  pa.A[1] = Xk;  pa.A[2] = Xv;
  pa.Bt[0] = WqT; pa.Bt[1] = WkT; pa.Bt[2] = WvT;
  pa.C[0] = qb;  pa.C[1] = kb;  pa.C[2] = vT;
  pa.bias[0] = bq; pa.bias[1] = bk; pa.bias[2] = bv;
  proj_gemm<<<dim3(16, 64, 3), 256, 0, stream>>>(pa);

  // scores[b] = q[b] @ k[b]^T : M=N=2048, K=1024, fp32 out. TN=64 -> 2048 blocks.
  gemm_f32<64><<<dim3(32, 16, 4), 256, 0, stream>>>(
      qb, kb, sc, 1024, 2048, 2048LL * 1024, 2048LL * 1024, 2048LL * 2048);

  // P = softmax(BETA * scores), bf16
  softmax_rows<<<8192, 256, 0, stream>>>(sc, P);

  // out[b] = P[b] @ v[b] : M=2048, N=1024, K=2048. TN=64 -> 1024 blocks.
  gemm_f32<64><<<dim3(16, 16, 4), 256, 0, stream>>>(
      P, vT, out, 2048, 1024, 2048LL * 2048, 1024LL * 2048, 2048LL * 1024);
}